// Round 16
// baseline (91.202 us; speedup 1.0000x reference)
//
#include <hip/hip_runtime.h>

// RandomHingeFern: B=4096, C_in=512, O=1024, D=10, L=2^10=1024
// out[b,o] = weights[o, leaf(b,o)] * min_d |x[b, ord[o,d]] - thr[o,d]|
//
// Kernel 1: transpose x [B][CIN] -> xT [CIN][B] (d_ws, 8 MB).
// Kernel 2: fern, vf4 b-pairing, max-TLP config: o-tile 8, 2048 blocks ->
//   8 blocks/CU, 32 waves/CU (8/SIMD) to hide L2 latency. lane handles 4
//   consecutive b; o wave-uniform (scalar ord/thr loads); 4 same-row weights
//   gathers per task. XCD-rectangle: per-XCD 2MB x + 2MB weights L2-resident.

#define B_TOT  4096
#define CIN    512
#define O_TOT  1024
#define DEPTH  10
#define LEAVES 1024
#define OSH_LD 268    // row stride (floats): mult of 4 (vf4-aligned), %32=12 -> ~2-way flush

typedef float vf4 __attribute__((ext_vector_type(4)));

// ---------------- Kernel 1: x -> xT (64x64 tiles via swizzled LDS) ----------
__global__ __launch_bounds__(256, 4) void transpose_kernel(
    const float* __restrict__ x,   // [B][CIN]
    float* __restrict__ xT)        // [CIN][B]
{
    __shared__ float tile[64 * 64];         // 16 KB, slot = r*64 + (c ^ r)
    const int t  = threadIdx.x;
    const int c0 = blockIdx.x * 64;         // channel tile (8)
    const int r0 = blockIdx.y * 64;         // batch tile  (64)

#pragma unroll
    for (int k = 0; k < 4; ++k) {
        const int id = k * 256 + t;         // 0..1023
        const int r  = id >> 4;             // 0..63
        const int c4 = id & 15;             // float4 col group
        const vf4 v = *reinterpret_cast<const vf4*>(
            x + (size_t)(r0 + r) * CIN + c0 + (c4 << 2));
        const int c = c4 << 2;
        tile[r * 64 + ((c + 0) ^ r)] = v.x;
        tile[r * 64 + ((c + 1) ^ r)] = v.y;
        tile[r * 64 + ((c + 2) ^ r)] = v.z;
        tile[r * 64 + ((c + 3) ^ r)] = v.w;
    }
    __syncthreads();

#pragma unroll
    for (int k = 0; k < 4; ++k) {
        const int id = k * 256 + t;
        const int c  = id >> 4;             // channel row of xT
        const int j4 = id & 15;             // b float4 group
        vf4 v;
        v.x = tile[(j4 * 4 + 0) * 64 + (c ^ (j4 * 4 + 0))];
        v.y = tile[(j4 * 4 + 1) * 64 + (c ^ (j4 * 4 + 1))];
        v.z = tile[(j4 * 4 + 2) * 64 + (c ^ (j4 * 4 + 2))];
        v.w = tile[(j4 * 4 + 3) * 64 + (c ^ (j4 * 4 + 3))];
        *reinterpret_cast<vf4*>(xT + (size_t)(c0 + c) * B_TOT + r0 + (j4 << 2)) = v;
    }
}

// ---------------- Kernel 2: fern (vf4 pairing, max TLP) ----------------
// 2048 blocks x 256 threads (4 waves). b-tile 256 (4 b per lane), o-tile 8.
// XCD rectangle: k=id&7, j=id>>3; b_t=(k&3)*4+(j&3)  in [0,16),
//                o_t=(k>>2)*64+(j>>2) in [0,128).
__global__ __launch_bounds__(256, 8) void fern_kernel(
    const float* __restrict__ xT,         // [CIN][B]
    const float* __restrict__ thresholds, // [O][DEPTH]
    const int*   __restrict__ ordinals,   // [O][DEPTH]
    const float* __restrict__ weights,    // [O][LEAVES]
    float*       __restrict__ out)        // [B][O]
{
    __shared__ float osh[8 * OSH_LD];     // 8.6 KB, [o_loc][4*lane..]

    const int t    = threadIdx.x;
    const int lane = t & 63;
    const int wv   = __builtin_amdgcn_readfirstlane(t >> 6);   // 0..3

    const int id = blockIdx.x;            // 0..2047
    const int k  = id & 7;                // XCD under %8 round-robin
    const int j  = id >> 3;               // 0..255
    const int b0 = ((k & 3) * 4 + (j & 3)) * 256;
    const int o0 = ((k >> 2) * 64 + (j >> 2)) * 8;
    const int bb = b0 + 4 * lane;

#pragma unroll
    for (int i = 0; i < 2; ++i) {
        const int ol = wv * 2 + i;                  // wave-uniform, 0..7
        const int o  = o0 + ol;
        const int*   op = ordinals   + o * DEPTH;   // SGPR base -> s_load
        const float* tp = thresholds + o * DEPTH;   // SGPR base -> s_load

        // 10 coalesced 1024B vf4 loads, all issued up front (deep MLP).
        vf4 xv[DEPTH];
#pragma unroll
        for (int d = 0; d < DEPTH; ++d)
            xv[d] = *reinterpret_cast<const vf4*>(
                xT + (size_t)op[d] * B_TOT + bb);

        int   leaf[4] = {0, 0, 0, 0};
        float mm[4]   = {1e30f, 1e30f, 1e30f, 1e30f};
#pragma unroll
        for (int d = 0; d < DEPTH; ++d) {
            const float thr = tp[d];
#pragma unroll
            for (int u = 0; u < 4; ++u) {
                const float g = xv[d][u] - thr;
                leaf[u] = (leaf[u] << 1) | (g > 0.0f ? 1 : 0);
                mm[u]   = fminf(mm[u], fabsf(g));
            }
        }
        const float* wrow = weights + (size_t)o * LEAVES;
        vf4 r;
#pragma unroll
        for (int u = 0; u < 4; ++u)
            r[u] = wrow[leaf[u]] * mm[u];           // 4 same-row gathers (L1-hot)
        *reinterpret_cast<vf4*>(&osh[ol * OSH_LD + 4 * lane]) = r;
    }
    __syncthreads();

    // ---- flush: 256 b x 8 o = 512 vf4, 2 per thread, 32B-coalesced NT
#pragma unroll
    for (int kk = 0; kk < 2; ++kk) {
        const int i  = kk * 256 + t;
        const int b  = i >> 1;               // 0..255
        const int oq = (i & 1) << 2;         // 0,4
        vf4 v;
        v.x = osh[(oq + 0) * OSH_LD + b];
        v.y = osh[(oq + 1) * OSH_LD + b];
        v.z = osh[(oq + 2) * OSH_LD + b];
        v.w = osh[(oq + 3) * OSH_LD + b];
        __builtin_nontemporal_store(v, reinterpret_cast<vf4*>(
            out + (size_t)(b0 + b) * O_TOT + o0 + oq));
    }
}

extern "C" void kernel_launch(void* const* d_in, const int* in_sizes, int n_in,
                              void* d_out, int out_size, void* d_ws, size_t ws_size,
                              hipStream_t stream) {
    const float* x          = (const float*)d_in[0];
    const float* thresholds = (const float*)d_in[1];
    const int*   ordinals   = (const int*)d_in[2];
    const float* weights    = (const float*)d_in[3];
    float*       out        = (float*)d_out;
    float*       xT         = (float*)d_ws;     // 8 MB

    dim3 tg(CIN / 64, B_TOT / 64);              // 8 x 64 = 512 blocks
    transpose_kernel<<<tg, 256, 0, stream>>>(x, xT);

    fern_kernel<<<2048, 256, 0, stream>>>(xT, thresholds, ordinals, weights, out);
}